// Round 11
// baseline (319.134 us; speedup 1.0000x reference)
//
#include <hip/hip_runtime.h>

#define B_ 512
#define T_ 512
#define V_ 96
#define H_ 128
#define K2F 2.8853900817779268f   // 2*log2(e): exp(2s) == exp2(K2F*s)

typedef _Float16 h2_t __attribute__((ext_vector_type(2)));

__device__ __forceinline__ h2_t as_h2(unsigned u) {
    union { unsigned u; h2_t h; } v; v.u = u; return v.h;
}
__device__ __forceinline__ unsigned as_u32(h2_t h) {
    union { h2_t h; unsigned u; } v; v.h = h; return v.u;
}
// v_cvt_pkrtz_f16_f32: pack 2 fp32 -> 2 fp16, return raw dword
__device__ __forceinline__ unsigned pkrtz_u32(float a, float b) {
    auto r = __builtin_amdgcn_cvt_pkrtz(a, b);
    union { decltype(r) h; unsigned u; } v; v.h = r; return v.u;
}
__device__ __forceinline__ float fdot2(h2_t a, h2_t b, float c) {
#if __has_builtin(__builtin_amdgcn_fdot2)
    return __builtin_amdgcn_fdot2(a, b, c, false);
#else
    return fmaf((float)a.x, (float)b.x, fmaf((float)a.y, (float)b.y, c));
#endif
}
template<int CTRL>
__device__ __forceinline__ float dpp_add(float x) {
    int y = __builtin_amdgcn_update_dpp(0, __float_as_int(x), CTRL, 0xF, 0xF, true);
    return x + __int_as_float(y);
}

// Pass 1a: recover the one-hot index per (b,t). x is exactly {0.0, 1.0}.
__global__ __launch_bounds__(256) void onehot_idx_kernel(
    const float4* __restrict__ x4, int n4, int* __restrict__ idx)
{
    int stride = gridDim.x * blockDim.x;
    for (int e4 = blockIdx.x * blockDim.x + threadIdx.x; e4 < n4; e4 += stride) {
        float4 v = x4[e4];
        int base = e4 * 4;
        if (v.x > 0.5f) idx[(base + 0) / V_] = (base + 0) % V_;
        if (v.y > 0.5f) idx[(base + 1) / V_] = (base + 1) % V_;
        if (v.z > 0.5f) idx[(base + 2) / V_] = (base + 2) % V_;
        if (v.w > 0.5f) idx[(base + 3) / V_] = (base + 3) % V_;
    }
}

// Pass 1b: xwT[v][h] = (W_ih[h][v] + b_ih[h] + b_hh[h]) * K2F  (fp32, global)
__global__ __launch_bounds__(256) void build_xwT_kernel(
    const float* __restrict__ W_ih, const float* __restrict__ b_ih,
    const float* __restrict__ b_hh, float* __restrict__ xwT)
{
    int e = blockIdx.x * blockDim.x + threadIdx.x;
    if (e < V_ * H_) {
        int v = e >> 7, h = e & 127;
        xwT[e] = (W_ih[h * V_ + v] + b_ih[h] + b_hh[h]) * K2F;
    }
}

// Pass 1c: pack W_hh into per-lane fp16 dwords (R7 layout, validated).
// rnn load: uint4 w4[r4] = whh2_u4[r4*64 + lane]; reg r = 4*r4+j;
// unit m = r>>5; pair p = r&31; value = pack(W_hh[4*(l>>1)+m][(l&1)*64+2p], +1)
__global__ __launch_bounds__(256) void build_whh2_kernel(
    const float* __restrict__ W_hh, unsigned* __restrict__ whh2)
{
    int D = blockIdx.x * blockDim.x + threadIdx.x;
    if (D < 64 * H_) {
        int r4  = D >> 8;
        int rem = D & 255;
        int l   = rem >> 2;
        int j   = rem & 3;
        int r   = (r4 << 2) + j;
        int m   = r >> 5;
        int p   = r & 31;
        int unit = ((l >> 1) << 2) + m;
        int k    = ((l & 1) << 6) + (p << 1);
        h2_t pk;
        pk.x = (_Float16)W_hh[unit * H_ + k];
        pk.y = (_Float16)W_hh[unit * H_ + k + 1];
        whh2[D] = as_u32(pk);
    }
}

// Pass 2: ONE WAVE per batch row -- no barriers in the step loop.
// R7/R9/R10 all showed VGPR_Count=84: the compiler SINKS the 32 weight
// loads into the loop (remat from L1 every step) instead of keeping
// 128 dwords live. The opaque asm below makes each loaded dword the
// output of an unknown transform -- rematerialization becomes illegal,
// so the weights must stay register-resident (budget = 512 via
// __launch_bounds__(64,1); no spill pressure).
__global__ __launch_bounds__(64, 1) void rnn_wave_kernel(
    const uint4* __restrict__ whh2, const float* __restrict__ xwT,
    const int*  __restrict__ idx,
    const float* __restrict__ W_fc, const float* __restrict__ b_fc,
    float* __restrict__ out)
{
    const int b  = blockIdx.x;
    const int l  = threadIdx.x;      // 0..63
    const int c  = l & 1;            // K-half
    const int u0 = (l >> 1) << 2;    // first of this lane's 4 units

    __shared__ int      idx_s[T_ + 1];
    __shared__ _Float16 hbuf[2][H_];

    for (int e = l; e < T_; e += 64) idx_s[e] = idx[b * T_ + e];
    if (l == 0) idx_s[T_] = 0;       // pad for t+1 prefetch at t=T-1
    hbuf[0][l]      = (_Float16)0.f;
    hbuf[0][l + 64] = (_Float16)0.f;

    uint4 w4[32];                    // 128 dwords, forced VGPR-resident
    #pragma unroll
    for (int r4 = 0; r4 < 32; ++r4) {
        w4[r4] = whh2[r4 * 64 + l];
        // opaque identity: kills load-rematerialization into the loop
        asm("" : "+v"(w4[r4].x), "+v"(w4[r4].y), "+v"(w4[r4].z), "+v"(w4[r4].w));
    }

    int cur = 0;
    float4 xw = *(const float4*)(xwT + idx_s[0] * H_ + u0);

    for (int t = 0; t < T_; ++t) {
        // prefetch next step's gather: global load, ~1 full step of slack
        const float4 xwn = *(const float4*)(xwT + idx_s[t + 1] * H_ + u0);

        // this lane's K-half of h: 8 broadcast b128 reads
        const uint4* hp = (const uint4*)((const char*)&hbuf[cur][0] + (c << 7));
        uint4 h4[8];
        #pragma unroll
        for (int i = 0; i < 8; ++i) h4[i] = hp[i];

        float a0 = 0.f, a1 = 0.f, a2 = 0.f, a3 = 0.f;
        #pragma unroll
        for (int p4 = 0; p4 < 8; ++p4) {
            const unsigned hx[4] = {h4[p4].x, h4[p4].y, h4[p4].z, h4[p4].w};
            const unsigned wx0[4] = {w4[ 0+p4].x, w4[ 0+p4].y, w4[ 0+p4].z, w4[ 0+p4].w};
            const unsigned wx1[4] = {w4[ 8+p4].x, w4[ 8+p4].y, w4[ 8+p4].z, w4[ 8+p4].w};
            const unsigned wx2[4] = {w4[16+p4].x, w4[16+p4].y, w4[16+p4].z, w4[16+p4].w};
            const unsigned wx3[4] = {w4[24+p4].x, w4[24+p4].y, w4[24+p4].z, w4[24+p4].w};
            #pragma unroll
            for (int j = 0; j < 4; ++j) {
                const h2_t hh = as_h2(hx[j]);
                a0 = fdot2(hh, as_h2(wx0[j]), a0);
                a1 = fdot2(hh, as_h2(wx1[j]), a1);
                a2 = fdot2(hh, as_h2(wx2[j]), a2);
                a3 = fdot2(hh, as_h2(wx3[j]), a3);
            }
        }
        // add partner K-half (lane c^1): single DPP xor1 stage
        a0 = dpp_add<0xB1>(a0); a1 = dpp_add<0xB1>(a1);
        a2 = dpp_add<0xB1>(a2); a3 = dpp_add<0xB1>(a3);

        // tanh(s) = 1 - 2/(exp2(K2F*s + xw) + 1)   (fp32)
        float e0 = __builtin_amdgcn_exp2f(fmaf(a0, K2F, xw.x));
        float e1 = __builtin_amdgcn_exp2f(fmaf(a1, K2F, xw.y));
        float e2 = __builtin_amdgcn_exp2f(fmaf(a2, K2F, xw.z));
        float e3 = __builtin_amdgcn_exp2f(fmaf(a3, K2F, xw.w));
        float h0 = 1.0f - 2.0f * __builtin_amdgcn_rcpf(e0 + 1.0f);
        float h1 = 1.0f - 2.0f * __builtin_amdgcn_rcpf(e1 + 1.0f);
        float h2v = 1.0f - 2.0f * __builtin_amdgcn_rcpf(e2 + 1.0f);
        float h3 = 1.0f - 2.0f * __builtin_amdgcn_rcpf(e3 + 1.0f);

        if (c == 0) {                         // 32 lanes write 8B each (2-way: free)
            *(uint2*)((char*)&hbuf[cur ^ 1][0] + (u0 << 1)) =
                make_uint2(pkrtz_u32(h0, h1), pkrtz_u32(h2v, h3));
        }
        cur ^= 1;
        xw = xwn;
    }

    // fc on final hidden state (one-time; scalar LDS reads are fine here)
    for (int v = l; v < V_; v += 64) {
        float acc = b_fc[v];
        const float4* wf = (const float4*)(W_fc + v * H_);
        #pragma unroll 8
        for (int k4 = 0; k4 < 32; ++k4) {
            float4 wv = wf[k4];
            acc = fmaf((float)hbuf[cur][4 * k4 + 0], wv.x, acc);
            acc = fmaf((float)hbuf[cur][4 * k4 + 1], wv.y, acc);
            acc = fmaf((float)hbuf[cur][4 * k4 + 2], wv.z, acc);
            acc = fmaf((float)hbuf[cur][4 * k4 + 3], wv.w, acc);
        }
        out[b * V_ + v] = acc;
    }
}

extern "C" void kernel_launch(void* const* d_in, const int* in_sizes, int n_in,
                              void* d_out, int out_size, void* d_ws, size_t ws_size,
                              hipStream_t stream)
{
    const float* x    = (const float*)d_in[0];
    const float* W_ih = (const float*)d_in[1];
    const float* b_ih = (const float*)d_in[2];
    const float* W_hh = (const float*)d_in[3];
    const float* b_hh = (const float*)d_in[4];
    const float* W_fc = (const float*)d_in[5];
    const float* b_fc = (const float*)d_in[6];
    float* out = (float*)d_out;

    int*      idx  = (int*)d_ws;                                    // 1 MiB
    float*    xwT  = (float*)((char*)d_ws + (size_t)B_ * T_ * 4);   // 48 KiB
    unsigned* whh2 = (unsigned*)((char*)xwT + (size_t)V_ * H_ * 4); // 32 KiB

    const int n4 = (B_ * T_ * V_) / 4;
    hipLaunchKernelGGL(onehot_idx_kernel, dim3(2048), dim3(256), 0, stream,
                       (const float4*)x, n4, idx);
    hipLaunchKernelGGL(build_xwT_kernel, dim3((V_ * H_ + 255) / 256), dim3(256),
                       0, stream, W_ih, b_ih, b_hh, xwT);
    hipLaunchKernelGGL(build_whh2_kernel, dim3((64 * H_ + 255) / 256), dim3(256),
                       0, stream, W_hh, whh2);
    hipLaunchKernelGGL(rnn_wave_kernel, dim3(B_), dim3(64), 0, stream,
                       (const uint4*)whh2, xwT, idx, W_fc, b_fc, out);
}

// Round 12
// 279.707 us; speedup vs baseline: 1.1410x; 1.1410x over previous
//
#include <hip/hip_runtime.h>

#define B_ 512
#define T_ 512
#define V_ 96
#define H_ 128
#define WPAD 132   // wihT row stride (dwords): 16B-aligned rows, 4-bank rotation
#define K2F 2.8853900817779268f   // 2*log2(e): exp(2s) == exp2(K2F*s)

typedef _Float16 h2_t __attribute__((ext_vector_type(2)));

__device__ __forceinline__ h2_t as_h2(unsigned u) {
    union { unsigned u; h2_t h; } v; v.u = u; return v.h;
}
__device__ __forceinline__ unsigned as_u32(h2_t h) {
    union { h2_t h; unsigned u; } v; v.h = h; return v.u;
}
// v_cvt_pkrtz_f16_f32: pack 2 fp32 -> 2 fp16, return raw dword
__device__ __forceinline__ unsigned pkrtz_u32(float a, float b) {
    auto r = __builtin_amdgcn_cvt_pkrtz(a, b);
    union { decltype(r) h; unsigned u; } v; v.h = r; return v.u;
}
__device__ __forceinline__ float fdot2(h2_t a, h2_t b, float c) {
#if __has_builtin(__builtin_amdgcn_fdot2)
    return __builtin_amdgcn_fdot2(a, b, c, false);
#else
    return fmaf((float)a.x, (float)b.x, fmaf((float)a.y, (float)b.y, c));
#endif
}
template<int CTRL>
__device__ __forceinline__ float dpp_add(float x) {
    int y = __builtin_amdgcn_update_dpp(0, __float_as_int(x), CTRL, 0xF, 0xF, true);
    return x + __int_as_float(y);
}

// Pass 1a: recover the one-hot index per (b,t). x is exactly {0.0, 1.0}.
__global__ __launch_bounds__(256) void onehot_idx_kernel(
    const float4* __restrict__ x4, int n4, int* __restrict__ idx)
{
    int stride = gridDim.x * blockDim.x;
    for (int e4 = blockIdx.x * blockDim.x + threadIdx.x; e4 < n4; e4 += stride) {
        float4 v = x4[e4];
        int base = e4 * 4;
        if (v.x > 0.5f) idx[(base + 0) / V_] = (base + 0) % V_;
        if (v.y > 0.5f) idx[(base + 1) / V_] = (base + 1) % V_;
        if (v.z > 0.5f) idx[(base + 2) / V_] = (base + 2) % V_;
        if (v.w > 0.5f) idx[(base + 3) / V_] = (base + 3) % V_;
    }
}

// Pass 1c: pack W_hh into per-lane fp16 dwords (R7 layout, validated).
// rnn load: uint4 w4[r4] = whh2_u4[r4*64 + lane]; reg r = 4*r4+j;
// unit m = r>>5; pair p = r&31; value = pack(W_hh[4*(l>>1)+m][(l&1)*64+2p], +1)
__global__ __launch_bounds__(256) void build_whh2_kernel(
    const float* __restrict__ W_hh, unsigned* __restrict__ whh2)
{
    int D = blockIdx.x * blockDim.x + threadIdx.x;
    if (D < 64 * H_) {
        int r4  = D >> 8;
        int rem = D & 255;
        int l   = rem >> 2;
        int j   = rem & 3;
        int r   = (r4 << 2) + j;
        int m   = r >> 5;
        int p   = r & 31;
        int unit = ((l >> 1) << 2) + m;
        int k    = ((l & 1) << 6) + (p << 1);
        h2_t pk;
        pk.x = (_Float16)W_hh[unit * H_ + k];
        pk.y = (_Float16)W_hh[unit * H_ + k + 1];
        whh2[D] = as_u32(pk);
    }
}

// Pass 2: ONE WAVE per batch row, no barriers, and -- the R12 change --
// ZERO vmem instructions inside the step loop. R7/R10's global xw
// prefetch forced a conservative s_waitcnt vmcnt(0) on xw's use each
// step (the just-issued next-step load is outstanding) = an L2 round
// trip on the critical path every iteration. The gather now comes from
// an LDS table (bias-folded, K2F-pre-scaled, transposed W_ih) staged
// once per block: the whole loop is one cheap lgkmcnt domain.
__global__ __launch_bounds__(64, 1) void rnn_wave_kernel(
    const uint4* __restrict__ whh2,
    const float* __restrict__ W_ih, const float* __restrict__ b_ih,
    const float* __restrict__ b_hh,
    const int*  __restrict__ idx,
    const float* __restrict__ W_fc, const float* __restrict__ b_fc,
    float* __restrict__ out)
{
    const int b  = blockIdx.x;
    const int l  = threadIdx.x;      // 0..63
    const int c  = l & 1;            // K-half
    const int u0 = (l >> 1) << 2;    // first of this lane's 4 units

    __shared__ float    wihT[V_][WPAD];   // ~50.7 KiB gather table
    __shared__ int      idx_s[T_ + 1];
    __shared__ _Float16 hbuf[2][H_];

    // Stage wihT[v][h] = (W_ih[h][v] + b_ih[h] + b_hh[h]) * K2F  (one-time)
    for (int e = l; e < V_ * H_; e += 64) {
        int hh = e / V_;
        int vv = e - hh * V_;
        wihT[vv][hh] = (W_ih[e] + b_ih[hh] + b_hh[hh]) * K2F;
    }
    for (int e = l; e < T_; e += 64) idx_s[e] = idx[b * T_ + e];
    if (l == 0) idx_s[T_] = 0;       // pad for t+1 lookahead at t=T-1
    hbuf[0][l]      = (_Float16)0.f;
    hbuf[0][l + 64] = (_Float16)0.f;

    uint4 w4[32];                    // 128 packed-fp16 dwords
    #pragma unroll
    for (int r4 = 0; r4 < 32; ++r4) w4[r4] = whh2[r4 * 64 + l];

    int cur = 0;
    int id  = idx_s[0];              // current step's char (register-carried)

    for (int t = 0; t < T_; ++t) {
        const int idn = idx_s[t + 1];                  // next step's char
        // gather ds_read issued here; result needed only at the exp2 stage
        // (~400 cy later) -- LDS latency fully hidden, no vmcnt anywhere.
        const float4 xw = *(const float4*)&wihT[id][u0];

        // this lane's K-half of h: 8 broadcast b128 reads
        const uint4* hp = (const uint4*)((const char*)&hbuf[cur][0] + (c << 7));
        uint4 h4[8];
        #pragma unroll
        for (int i = 0; i < 8; ++i) h4[i] = hp[i];

        float a0 = 0.f, a1 = 0.f, a2 = 0.f, a3 = 0.f;
        #pragma unroll
        for (int p4 = 0; p4 < 8; ++p4) {
            const unsigned hx[4] = {h4[p4].x, h4[p4].y, h4[p4].z, h4[p4].w};
            const unsigned wx0[4] = {w4[ 0+p4].x, w4[ 0+p4].y, w4[ 0+p4].z, w4[ 0+p4].w};
            const unsigned wx1[4] = {w4[ 8+p4].x, w4[ 8+p4].y, w4[ 8+p4].z, w4[ 8+p4].w};
            const unsigned wx2[4] = {w4[16+p4].x, w4[16+p4].y, w4[16+p4].z, w4[16+p4].w};
            const unsigned wx3[4] = {w4[24+p4].x, w4[24+p4].y, w4[24+p4].z, w4[24+p4].w};
            #pragma unroll
            for (int j = 0; j < 4; ++j) {
                const h2_t hh = as_h2(hx[j]);
                a0 = fdot2(hh, as_h2(wx0[j]), a0);
                a1 = fdot2(hh, as_h2(wx1[j]), a1);
                a2 = fdot2(hh, as_h2(wx2[j]), a2);
                a3 = fdot2(hh, as_h2(wx3[j]), a3);
            }
        }
        // add partner K-half (lane c^1): single DPP xor1 stage
        a0 = dpp_add<0xB1>(a0); a1 = dpp_add<0xB1>(a1);
        a2 = dpp_add<0xB1>(a2); a3 = dpp_add<0xB1>(a3);

        // tanh(s) = 1 - 2/(exp2(K2F*s + xw) + 1)   (fp32)
        float e0 = __builtin_amdgcn_exp2f(fmaf(a0, K2F, xw.x));
        float e1 = __builtin_amdgcn_exp2f(fmaf(a1, K2F, xw.y));
        float e2 = __builtin_amdgcn_exp2f(fmaf(a2, K2F, xw.z));
        float e3 = __builtin_amdgcn_exp2f(fmaf(a3, K2F, xw.w));
        float h0 = 1.0f - 2.0f * __builtin_amdgcn_rcpf(e0 + 1.0f);
        float h1 = 1.0f - 2.0f * __builtin_amdgcn_rcpf(e1 + 1.0f);
        float h2v = 1.0f - 2.0f * __builtin_amdgcn_rcpf(e2 + 1.0f);
        float h3 = 1.0f - 2.0f * __builtin_amdgcn_rcpf(e3 + 1.0f);

        if (c == 0) {                 // 32 lanes write 8B each (2-way: free)
            *(uint2*)((char*)&hbuf[cur ^ 1][0] + (u0 << 1)) =
                make_uint2(pkrtz_u32(h0, h1), pkrtz_u32(h2v, h3));
        }
        cur ^= 1;
        id = idn;
    }

    // fc on final hidden state (one-time; scalar LDS reads are fine here)
    for (int v = l; v < V_; v += 64) {
        float acc = b_fc[v];
        const float4* wf = (const float4*)(W_fc + v * H_);
        #pragma unroll 8
        for (int k4 = 0; k4 < 32; ++k4) {
            float4 wv = wf[k4];
            acc = fmaf((float)hbuf[cur][4 * k4 + 0], wv.x, acc);
            acc = fmaf((float)hbuf[cur][4 * k4 + 1], wv.y, acc);
            acc = fmaf((float)hbuf[cur][4 * k4 + 2], wv.z, acc);
            acc = fmaf((float)hbuf[cur][4 * k4 + 3], wv.w, acc);
        }
        out[b * V_ + v] = acc;
    }
}

extern "C" void kernel_launch(void* const* d_in, const int* in_sizes, int n_in,
                              void* d_out, int out_size, void* d_ws, size_t ws_size,
                              hipStream_t stream)
{
    const float* x    = (const float*)d_in[0];
    const float* W_ih = (const float*)d_in[1];
    const float* b_ih = (const float*)d_in[2];
    const float* W_hh = (const float*)d_in[3];
    const float* b_hh = (const float*)d_in[4];
    const float* W_fc = (const float*)d_in[5];
    const float* b_fc = (const float*)d_in[6];
    float* out = (float*)d_out;

    int*      idx  = (int*)d_ws;                                   // 1 MiB
    unsigned* whh2 = (unsigned*)((char*)d_ws + (size_t)B_ * T_ * 4); // 32 KiB

    const int n4 = (B_ * T_ * V_) / 4;
    hipLaunchKernelGGL(onehot_idx_kernel, dim3(2048), dim3(256), 0, stream,
                       (const float4*)x, n4, idx);
    hipLaunchKernelGGL(build_whh2_kernel, dim3((64 * H_ + 255) / 256), dim3(256),
                       0, stream, W_hh, whh2);
    hipLaunchKernelGGL(rnn_wave_kernel, dim3(B_), dim3(64), 0, stream,
                       (const uint4*)whh2, W_ih, b_ih, b_hh, idx, W_fc, b_fc, out);
}